// Round 1
// baseline (1036.068 us; speedup 1.0000x reference)
//
#include <hip/hip_runtime.h>

#define DM     1024
#define DFF    4096
#define NE     8
#define TT     8192
#define CHUNK  1024
#define NCHUNK 4
#define CAP    8192
#define TILE   128
#define NKT    16   // K=1024 / BK=64

typedef __bf16 bf16x8 __attribute__((ext_vector_type(8)));
typedef float  f32x4  __attribute__((ext_vector_type(4)));
typedef unsigned short u16;
typedef unsigned int   u32;

__device__ __forceinline__ u16 f2bf(float f) {
    u32 u = __builtin_bit_cast(u32, f);
    u += 0x7fffu + ((u >> 16) & 1u);   // round-to-nearest-even
    return (u16)(u >> 16);
}

// ---------------- router: logits, softmax, top-2, lists, prob sums ----------------
__global__ __launch_bounds__(256) void router_k(
    const float* __restrict__ x, const float* __restrict__ Wr, const float* __restrict__ br,
    int* __restrict__ expert_count, float* __restrict__ prob_sum,
    int* __restrict__ list_token, float* __restrict__ list_w)
{
    __shared__ float ps[NE];
    int tid = threadIdx.x;
    if (tid < NE) ps[tid] = 0.f;
    __syncthreads();
    int w = tid >> 6, l = tid & 63;
    int token = blockIdx.x * 4 + w;
    float acc[NE];
#pragma unroll
    for (int e = 0; e < NE; ++e) acc[e] = 0.f;
    const float* xr = x + (size_t)token * DM;
#pragma unroll
    for (int i = 0; i < DM / 64; ++i) {
        int k = l + i * 64;
        float xv = xr[k];
        const float4* wr4 = reinterpret_cast<const float4*>(Wr + k * NE);
        float4 wa = wr4[0], wb = wr4[1];
        acc[0] += xv * wa.x; acc[1] += xv * wa.y; acc[2] += xv * wa.z; acc[3] += xv * wa.w;
        acc[4] += xv * wb.x; acc[5] += xv * wb.y; acc[6] += xv * wb.z; acc[7] += xv * wb.w;
    }
#pragma unroll
    for (int off = 32; off >= 1; off >>= 1) {
#pragma unroll
        for (int e = 0; e < NE; ++e) acc[e] += __shfl_xor(acc[e], off);
    }
    if (l == 0) {
        float li[NE], m = -1e30f;
#pragma unroll
        for (int e = 0; e < NE; ++e) { li[e] = (acc[e] + br[e]) * (1.0f / 0.7f); m = fmaxf(m, li[e]); }
        float p[NE], s = 0.f;
#pragma unroll
        for (int e = 0; e < NE; ++e) { p[e] = __expf(li[e] - m); s += p[e]; }
        float inv = 1.f / s;
#pragma unroll
        for (int e = 0; e < NE; ++e) p[e] *= inv;
#pragma unroll
        for (int e = 0; e < NE; ++e) atomicAdd(&ps[e], p[e]);
        float v1 = -1.f, v2 = -1.f; int e1 = 0, e2 = 0;
#pragma unroll
        for (int e = 0; e < NE; ++e) {      // ascending scan: ties keep lower index (top_k semantics)
            float pe = p[e];
            if (pe > v1)      { v2 = v1; e2 = e1; v1 = pe; e1 = e; }
            else if (pe > v2) { v2 = pe; e2 = e; }
        }
        float denom = v1 + v2 + 1e-6f;
        float w1 = v1 / denom, w2 = v2 / denom;
        int q1 = atomicAdd(&expert_count[e1], 1);
        list_token[e1 * CAP + q1] = token; list_w[e1 * CAP + q1] = w1;
        int q2 = atomicAdd(&expert_count[e2], 1);
        list_token[e2 * CAP + q2] = token; list_w[e2 * CAP + q2] = w2;
    }
    __syncthreads();
    if (tid < NE) atomicAdd(&prob_sum[tid], ps[tid]);
}

// ---------------- scan: padded offsets + aux loss ----------------
__global__ void scan_aux_k(const int* __restrict__ expert_count, const float* __restrict__ prob_sum,
                           int* __restrict__ padded_count, int* __restrict__ poffsets,
                           float* __restrict__ aux_out)
{
    if (threadIdx.x == 0 && blockIdx.x == 0) {
        int off = 0; float aux = 0.f;
        for (int e = 0; e < NE; ++e) {
            int c = expert_count[e];
            int pc = (c + TILE - 1) / TILE * TILE;
            poffsets[e] = off; padded_count[e] = pc; off += pc;
            aux += ((float)c / (float)TT) * (prob_sum[e] / (float)TT);
        }
        aux_out[0] = aux * (float)NE;
    }
}

// ---------------- gather routed x rows -> bf16 Xg (zero-fill padding) ----------------
__global__ __launch_bounds__(256) void gather_k(
    const float* __restrict__ x, const int* __restrict__ list_token,
    const int* __restrict__ expert_count, const int* __restrict__ padded_count,
    const int* __restrict__ poffsets, u16* __restrict__ Xg)
{
    int e = blockIdx.y;
    int p0 = blockIdx.x * 8;
    if (p0 >= padded_count[e]) return;
    int tid = threadIdx.x;
    int rr = tid >> 5, cl = tid & 31;
    int p = p0 + rr;
    int g = poffsets[e] + p;
    u16* dst = Xg + (size_t)g * DM;
    bool valid = p < expert_count[e];
    int tok = valid ? list_token[e * CAP + p] : 0;
    const float* src = x + (size_t)tok * DM;
#pragma unroll
    for (int i = 0; i < 4; ++i) {
        int c0 = cl * 8 + i * 256;
        uint4 v;
        if (valid) {
            float4 f0 = *reinterpret_cast<const float4*>(src + c0);
            float4 f1 = *reinterpret_cast<const float4*>(src + c0 + 4);
            v.x = f2bf(f0.x) | ((u32)f2bf(f0.y) << 16);
            v.y = f2bf(f0.z) | ((u32)f2bf(f0.w) << 16);
            v.z = f2bf(f1.x) | ((u32)f2bf(f1.y) << 16);
            v.w = f2bf(f1.z) | ((u32)f2bf(f1.w) << 16);
        } else {
            v.x = 0; v.y = 0; v.z = 0; v.w = 0;
        }
        *reinterpret_cast<uint4*>(dst + c0) = v;
    }
}

// ---------------- transpose + fp32->bf16 convert of a 1024x1024 weight slice ----------------
// src element: src[e*4194304 + base + k*rs + j]  (k,j in [0,1024))
// dst element: dst[e*1048576 + j*1024 + k]       ([N][K] layout for K-contiguous B fragments)
__global__ __launch_bounds__(256) void convt_k(
    const float* __restrict__ src, u16* __restrict__ dst, long base, int rs)
{
    __shared__ float tile[64][65];
    int e = blockIdx.z;
    int k0 = blockIdx.x * 64, j0 = blockIdx.y * 64;
    const float* s = src + (size_t)e * 4194304 + base;
    int tid = threadIdx.x;
    {
        int jj = (tid & 15) * 4, kb = tid >> 4;
#pragma unroll
        for (int i = 0; i < 4; ++i) {
            int k = kb + i * 16;
            float4 v = *reinterpret_cast<const float4*>(s + (size_t)(k0 + k) * rs + j0 + jj);
            tile[k][jj] = v.x; tile[k][jj + 1] = v.y; tile[k][jj + 2] = v.z; tile[k][jj + 3] = v.w;
        }
    }
    __syncthreads();
    {
        int kk = (tid & 15) * 4, jb = tid >> 4;
        u16* d = dst + (size_t)e * 1048576;
#pragma unroll
        for (int i = 0; i < 4; ++i) {
            int j = jb + i * 16;
            uint2 q;
            q.x = f2bf(tile[kk][j])     | ((u32)f2bf(tile[kk + 1][j]) << 16);
            q.y = f2bf(tile[kk + 2][j]) | ((u32)f2bf(tile[kk + 3][j]) << 16);
            *reinterpret_cast<uint2*>(d + (size_t)(j0 + j) * 1024 + k0 + kk) = q;
        }
    }
}

// ---------------- shared 128x128 bf16 GEMM mainloop (K=1024, BK=64, dbuf LDS) ----------------
// A: 128 rows x 1024 K, row-major (stride 1024). B: 128 "n" rows x 1024 K ([N][K]).
// LDS chunk swizzle c8 ^= (row&7) breaks the row-major 16-way bank conflict.
__device__ __forceinline__ void gemm_tile(
    const u16* __restrict__ Arows, const u16* __restrict__ Brows,
    char* smem, f32x4 acc[4][4])
{
    int tid = threadIdx.x;
    int l = tid & 63, lane16 = l & 15, hi = l >> 4;
    int wm = (tid >> 6) & 1, wn = tid >> 7;

    uint4 ra[4], rb[4];

    auto loadg = [&](const u16* rows, int kt, uint4* r4) {
#pragma unroll
        for (int i = 0; i < 4; ++i) {
            int s = i * 256 + tid;
            int row = s >> 3, c8 = s & 7;
            r4[i] = *reinterpret_cast<const uint4*>(rows + (size_t)row * 1024 + kt * 64 + c8 * 8);
        }
    };
    auto stlds = [&](char* buf, const uint4* r4) {
#pragma unroll
        for (int i = 0; i < 4; ++i) {
            int s = i * 256 + tid;
            int row = s >> 3, c8 = s & 7;
            int wc = row * 8 + (c8 ^ (row & 7));
            *reinterpret_cast<uint4*>(buf + wc * 16) = r4[i];
        }
    };

    loadg(Arows, 0, ra); loadg(Brows, 0, rb);
    stlds(smem, ra); stlds(smem + 16384, rb);
    __syncthreads();
    int cur = 0;
    for (int kt = 0; kt < NKT; ++kt) {
        if (kt + 1 < NKT) { loadg(Arows, kt + 1, ra); loadg(Brows, kt + 1, rb); }
        const char* bufA = smem + cur * 32768;
        const char* bufB = bufA + 16384;
#pragma unroll
        for (int kk = 0; kk < 2; ++kk) {
            bf16x8 af[4], bb[4];
#pragma unroll
            for (int mi = 0; mi < 4; ++mi) {
                int row = wm * 64 + mi * 16 + lane16;
                int ch = (kk * 4 + hi) ^ (row & 7);
                af[mi] = *reinterpret_cast<const bf16x8*>(bufA + (row * 8 + ch) * 16);
            }
#pragma unroll
            for (int ni = 0; ni < 4; ++ni) {
                int row = wn * 64 + ni * 16 + lane16;
                int ch = (kk * 4 + hi) ^ (row & 7);
                bb[ni] = *reinterpret_cast<const bf16x8*>(bufB + (row * 8 + ch) * 16);
            }
#pragma unroll
            for (int mi = 0; mi < 4; ++mi)
#pragma unroll
                for (int ni = 0; ni < 4; ++ni)
                    acc[mi][ni] = __builtin_amdgcn_mfma_f32_16x16x32_bf16(af[mi], bb[ni], acc[mi][ni], 0, 0, 0);
        }
        if (kt + 1 < NKT) {
            char* nb = smem + (cur ^ 1) * 32768;
            stlds(nb, ra); stlds(nb + 16384, rb);
        }
        __syncthreads();
        cur ^= 1;
    }
}

// ---------------- GEMM1: H = silu(Xg @ W1c + b1), bf16 out ----------------
__global__ __launch_bounds__(256, 2) void gemm1_k(
    const u16* __restrict__ Xg, const u16* __restrict__ W1c, const float* __restrict__ b1,
    int chunk, const int* __restrict__ padded_count, const int* __restrict__ poffsets,
    u16* __restrict__ H)
{
    __shared__ char smem[65536];
    int e = blockIdx.z, rb = blockIdx.y, cb = blockIdx.x;
    if (rb * TILE >= padded_count[e]) return;
    int row0 = poffsets[e] + rb * TILE;
    const u16* Arows = Xg + (size_t)row0 * 1024;
    const u16* Brows = W1c + (size_t)e * 1048576 + (size_t)cb * TILE * 1024;
    f32x4 acc[4][4];
#pragma unroll
    for (int i = 0; i < 4; ++i)
#pragma unroll
        for (int j = 0; j < 4; ++j) { acc[i][j][0]=0.f; acc[i][j][1]=0.f; acc[i][j][2]=0.f; acc[i][j][3]=0.f; }
    gemm_tile(Arows, Brows, smem, acc);

    int tid = threadIdx.x;
    int l = tid & 63, lane16 = l & 15, hi = l >> 4;
    int wm = (tid >> 6) & 1, wn = tid >> 7;
    const float* b1e = b1 + (size_t)e * DFF + (size_t)chunk * CHUNK;
#pragma unroll
    for (int mi = 0; mi < 4; ++mi) {
#pragma unroll
        for (int ni = 0; ni < 4; ++ni) {
            int col = cb * TILE + wn * 64 + ni * 16 + lane16;
            float bv = b1e[col];
#pragma unroll
            for (int r = 0; r < 4; ++r) {
                int grow = row0 + wm * 64 + mi * 16 + hi * 4 + r;
                float z = acc[mi][ni][r] + bv;
                float hval = z / (1.f + __expf(-z));
                H[(size_t)grow * 1024 + col] = f2bf(hval);
            }
        }
    }
}

// ---------------- GEMM2: out[token] += w * (H @ W2c + b2), atomic scatter ----------------
__global__ __launch_bounds__(256, 2) void gemm2_k(
    const u16* __restrict__ Hb, const u16* __restrict__ W2c, const float* __restrict__ b2,
    int addbias, const int* __restrict__ expert_count, const int* __restrict__ padded_count,
    const int* __restrict__ poffsets, const int* __restrict__ list_token,
    const float* __restrict__ list_w, float* __restrict__ out)
{
    __shared__ char smem[65536];
    int e = blockIdx.z, rb = blockIdx.y, cb = blockIdx.x;
    if (rb * TILE >= padded_count[e]) return;
    int row0 = poffsets[e] + rb * TILE;
    const u16* Arows = Hb + (size_t)row0 * 1024;
    const u16* Brows = W2c + (size_t)e * 1048576 + (size_t)cb * TILE * 1024;
    f32x4 acc[4][4];
#pragma unroll
    for (int i = 0; i < 4; ++i)
#pragma unroll
        for (int j = 0; j < 4; ++j) { acc[i][j][0]=0.f; acc[i][j][1]=0.f; acc[i][j][2]=0.f; acc[i][j][3]=0.f; }
    gemm_tile(Arows, Brows, smem, acc);

    int tid = threadIdx.x;
    int l = tid & 63, lane16 = l & 15, hi = l >> 4;
    int wm = (tid >> 6) & 1, wn = tid >> 7;
    int cnt = expert_count[e];
#pragma unroll
    for (int mi = 0; mi < 4; ++mi) {
#pragma unroll
        for (int r = 0; r < 4; ++r) {
            int p = rb * TILE + wm * 64 + mi * 16 + hi * 4 + r;
            if (p < cnt) {
                int tok = list_token[e * CAP + p];
                float wgt = list_w[e * CAP + p];
                float* orow = out + (size_t)tok * DM;
#pragma unroll
                for (int ni = 0; ni < 4; ++ni) {
                    int col = cb * TILE + wn * 64 + ni * 16 + lane16;
                    float v = acc[mi][ni][r];
                    if (addbias) v += b2[e * DM + col];
                    atomicAdd(orow + col, wgt * v);
                }
            }
        }
    }
}

extern "C" void kernel_launch(void* const* d_in, const int* in_sizes, int n_in,
                              void* d_out, int out_size, void* d_ws, size_t ws_size,
                              hipStream_t stream) {
    (void)in_sizes; (void)n_in; (void)out_size; (void)ws_size;
    const float* x  = (const float*)d_in[0];
    const float* Wr = (const float*)d_in[1];
    const float* br = (const float*)d_in[2];
    const float* W1 = (const float*)d_in[3];
    const float* b1 = (const float*)d_in[4];
    const float* W2 = (const float*)d_in[5];
    const float* b2 = (const float*)d_in[6];
    float* out = (float*)d_out;   // [8192*1024] out, then [1] aux

    char* ws = (char*)d_ws;
    int*   expert_count = (int*)(ws + 0);      // 32 B
    float* prob_sum     = (float*)(ws + 32);   // 32 B
    int*   padded_count = (int*)(ws + 64);     // 32 B
    int*   poffsets     = (int*)(ws + 96);     // 32 B
    int*   list_token   = (int*)(ws + 256);                // 8*8192*4 = 256 KiB
    float* list_w       = (float*)(ws + 256 + 262144);     // 256 KiB
    u16*   Xg  = (u16*)(ws + 524544);       // 17408*1024*2 = 35,651,584
    u16*   Hb  = (u16*)(ws + 36176128);     // 35,651,584
    u16*   W1c = (u16*)(ws + 71827712);     // 16,777,216
    u16*   W2c = (u16*)(ws + 88604928);     // 16,777,216  -> total ~105.4 MB

    hipMemsetAsync(d_out, 0, (size_t)TT * DM * sizeof(float), stream);  // out accumulated atomically
    hipMemsetAsync(ws, 0, 64, stream);                                  // counts + prob sums

    router_k<<<TT / 4, 256, 0, stream>>>(x, Wr, br, expert_count, prob_sum, list_token, list_w);
    scan_aux_k<<<1, 64, 0, stream>>>(expert_count, prob_sum, padded_count, poffsets,
                                     out + (size_t)TT * DM);
    gather_k<<<dim3(1024, 8), 256, 0, stream>>>(x, list_token, expert_count, padded_count, poffsets, Xg);

    for (int c = 0; c < NCHUNK; ++c) {
        convt_k<<<dim3(16, 16, 8), 256, 0, stream>>>(W1, W1c, (long)c * 1024, DFF);      // W1[e][k][c*1024+j] -> [j][k]
        convt_k<<<dim3(16, 16, 8), 256, 0, stream>>>(W2, W2c, (long)c * 1048576, DM);    // W2[e][c*1024+k][j] -> [j][k]
        gemm1_k<<<dim3(8, 64, 8), 256, 0, stream>>>(Xg, W1c, b1, c, padded_count, poffsets, Hb);
        gemm2_k<<<dim3(8, 64, 8), 256, 0, stream>>>(Hb, W2c, b2, (c == 0) ? 1 : 0,
                                                    expert_count, padded_count, poffsets,
                                                    list_token, list_w, out);
    }
}

// Round 2
// 831.574 us; speedup vs baseline: 1.2459x; 1.2459x over previous
//
#include <hip/hip_runtime.h>

#define DM     1024
#define DFF    4096
#define NE     8
#define TT     8192
#define CHUNK  1024
#define NCHUNK 4
#define CAP    8192
#define TILE   128
#define NKT    16   // K=1024 / BK=64
#define RTOK   32   // router tokens per block

typedef __bf16 bf16x8 __attribute__((ext_vector_type(8)));
typedef float  f32x4  __attribute__((ext_vector_type(4)));
typedef unsigned short u16;
typedef unsigned int   u32;

__device__ __forceinline__ u16 f2bf(float f) {
    u32 u = __builtin_bit_cast(u32, f);
    u += 0x7fffu + ((u >> 16) & 1u);   // round-to-nearest-even
    return (u16)(u >> 16);
}

__device__ __forceinline__ void gload_lds16(const void* g, void* l) {
    __builtin_amdgcn_global_load_lds(
        (const __attribute__((address_space(1))) void*)g,
        (__attribute__((address_space(3))) void*)l,
        16, 0, 0);
}

// ---------------- router: block-aggregated top-2 routing (8 global atomics/block) ----------------
__global__ __launch_bounds__(256) void router_k(
    const float* __restrict__ x, const float* __restrict__ Wr, const float* __restrict__ br,
    int* __restrict__ expert_count, float* __restrict__ prob_sum,
    int* __restrict__ list_token, float* __restrict__ list_w)
{
    __shared__ float wrT[NE][DM];       // 32 KB, Wr transposed [e][k]
    __shared__ float ps[NE];
    __shared__ int   lcount[NE];
    __shared__ int   lbase[NE];
    __shared__ int   lexp[RTOK * 2];
    __shared__ float lw[RTOK * 2];
    __shared__ int   lslot[RTOK * 2];

    int tid = threadIdx.x;
    if (tid < NE) { ps[tid] = 0.f; lcount[tid] = 0; }
    // stage Wr transposed: flat f = k*8+e  ->  wrT[e][k]
#pragma unroll
    for (int it = 0; it < 8; ++it) {
        int f = tid * 4 + it * 1024;
        float4 v = *reinterpret_cast<const float4*>(Wr + f);
        int e0 = f & 7, k = f >> 3;
        wrT[e0][k] = v.x; wrT[e0 + 1][k] = v.y; wrT[e0 + 2][k] = v.z; wrT[e0 + 3][k] = v.w;
    }
    __syncthreads();

    int w = tid >> 6, l = tid & 63;
    for (int j = 0; j < RTOK / 4; ++j) {     // each wave: 8 tokens
        int ti = w * (RTOK / 4) + j;
        int token = blockIdx.x * RTOK + ti;
        const float* xr = x + (size_t)token * DM;
        float acc[NE];
#pragma unroll
        for (int e = 0; e < NE; ++e) acc[e] = 0.f;
#pragma unroll
        for (int i = 0; i < 4; ++i) {
            float4 xv = *reinterpret_cast<const float4*>(xr + i * 256 + l * 4);
#pragma unroll
            for (int e = 0; e < NE; ++e) {
                float4 wv = *reinterpret_cast<const float4*>(&wrT[e][i * 256 + l * 4]);
                acc[e] += xv.x * wv.x + xv.y * wv.y + xv.z * wv.z + xv.w * wv.w;
            }
        }
#pragma unroll
        for (int off = 32; off >= 1; off >>= 1) {
#pragma unroll
            for (int e = 0; e < NE; ++e) acc[e] += __shfl_xor(acc[e], off);
        }
        if (l == 0) {
            float li[NE], m = -1e30f;
#pragma unroll
            for (int e = 0; e < NE; ++e) { li[e] = (acc[e] + br[e]) * (1.0f / 0.7f); m = fmaxf(m, li[e]); }
            float p[NE], s = 0.f;
#pragma unroll
            for (int e = 0; e < NE; ++e) { p[e] = __expf(li[e] - m); s += p[e]; }
            float inv = 1.f / s;
#pragma unroll
            for (int e = 0; e < NE; ++e) { p[e] *= inv; atomicAdd(&ps[e], p[e]); }
            float v1 = -1.f, v2 = -1.f; int e1 = 0, e2 = 0;
#pragma unroll
            for (int e = 0; e < NE; ++e) {   // ascending scan: ties keep lower index (top_k semantics)
                float pe = p[e];
                if (pe > v1)      { v2 = v1; e2 = e1; v1 = pe; e1 = e; }
                else if (pe > v2) { v2 = pe; e2 = e; }
            }
            float denom = v1 + v2 + 1e-6f;
            lexp[2 * ti]     = e1; lw[2 * ti]     = v1 / denom; lslot[2 * ti]     = atomicAdd(&lcount[e1], 1);
            lexp[2 * ti + 1] = e2; lw[2 * ti + 1] = v2 / denom; lslot[2 * ti + 1] = atomicAdd(&lcount[e2], 1);
        }
    }
    __syncthreads();
    if (tid < NE) {
        lbase[tid] = atomicAdd(&expert_count[tid], lcount[tid]);
        atomicAdd(&prob_sum[tid], ps[tid]);
    }
    __syncthreads();
    if (tid < RTOK * 2) {
        int e = lexp[tid];
        int g = lbase[e] + lslot[tid];
        list_token[e * CAP + g] = blockIdx.x * RTOK + (tid >> 1);
        list_w[e * CAP + g] = lw[tid];
    }
}

// ---------------- scan: padded offsets + aux loss ----------------
__global__ void scan_aux_k(const int* __restrict__ expert_count, const float* __restrict__ prob_sum,
                           int* __restrict__ padded_count, int* __restrict__ poffsets,
                           float* __restrict__ aux_out)
{
    if (threadIdx.x == 0 && blockIdx.x == 0) {
        int off = 0; float aux = 0.f;
        for (int e = 0; e < NE; ++e) {
            int c = expert_count[e];
            int pc = (c + TILE - 1) / TILE * TILE;
            poffsets[e] = off; padded_count[e] = pc; off += pc;
            aux += ((float)c / (float)TT) * (prob_sum[e] / (float)TT);
        }
        aux_out[0] = aux * (float)NE;
    }
}

// ---------------- gather routed x rows -> bf16 Xg (zero-fill padding) ----------------
__global__ __launch_bounds__(256) void gather_k(
    const float* __restrict__ x, const int* __restrict__ list_token,
    const int* __restrict__ expert_count, const int* __restrict__ padded_count,
    const int* __restrict__ poffsets, u16* __restrict__ Xg)
{
    int e = blockIdx.y;
    int p0 = blockIdx.x * 8;
    if (p0 >= padded_count[e]) return;
    int tid = threadIdx.x;
    int rr = tid >> 5, cl = tid & 31;
    int p = p0 + rr;
    int g = poffsets[e] + p;
    u16* dst = Xg + (size_t)g * DM;
    bool valid = p < expert_count[e];
    int tok = valid ? list_token[e * CAP + p] : 0;
    const float* src = x + (size_t)tok * DM;
#pragma unroll
    for (int i = 0; i < 4; ++i) {
        int c0 = cl * 8 + i * 256;
        uint4 v;
        if (valid) {
            float4 f0 = *reinterpret_cast<const float4*>(src + c0);
            float4 f1 = *reinterpret_cast<const float4*>(src + c0 + 4);
            v.x = f2bf(f0.x) | ((u32)f2bf(f0.y) << 16);
            v.y = f2bf(f0.z) | ((u32)f2bf(f0.w) << 16);
            v.z = f2bf(f1.x) | ((u32)f2bf(f1.y) << 16);
            v.w = f2bf(f1.z) | ((u32)f2bf(f1.w) << 16);
        } else {
            v.x = 0; v.y = 0; v.z = 0; v.w = 0;
        }
        *reinterpret_cast<uint4*>(dst + c0) = v;
    }
}

// ---------------- transpose + fp32->bf16 convert of a 1024x1024 weight slice ----------------
__global__ __launch_bounds__(256) void convt_k(
    const float* __restrict__ src, u16* __restrict__ dst, long base, int rs)
{
    __shared__ float tile[64][65];
    int e = blockIdx.z;
    int k0 = blockIdx.x * 64, j0 = blockIdx.y * 64;
    const float* s = src + (size_t)e * 4194304 + base;
    int tid = threadIdx.x;
    {
        int jj = (tid & 15) * 4, kb = tid >> 4;
#pragma unroll
        for (int i = 0; i < 4; ++i) {
            int k = kb + i * 16;
            float4 v = *reinterpret_cast<const float4*>(s + (size_t)(k0 + k) * rs + j0 + jj);
            tile[k][jj] = v.x; tile[k][jj + 1] = v.y; tile[k][jj + 2] = v.z; tile[k][jj + 3] = v.w;
        }
    }
    __syncthreads();
    {
        int kk = (tid & 15) * 4, jb = tid >> 4;
        u16* d = dst + (size_t)e * 1048576;
#pragma unroll
        for (int i = 0; i < 4; ++i) {
            int j = jb + i * 16;
            uint2 q;
            q.x = f2bf(tile[kk][j])     | ((u32)f2bf(tile[kk + 1][j]) << 16);
            q.y = f2bf(tile[kk + 2][j]) | ((u32)f2bf(tile[kk + 3][j]) << 16);
            *reinterpret_cast<uint2*>(d + (size_t)(j0 + j) * 1024 + k0 + kk) = q;
        }
    }
}

// ---------------- shared 128x128 bf16 GEMM mainloop (K=1024, BK=64, dbuf LDS, gload_lds) ----------------
// LDS dest is LINEAR (gload_lds requirement); bank-conflict swizzle achieved by
// pre-swizzling the per-lane GLOBAL source chunk: slot (row,c) holds global chunk c^(row&7).
__device__ __forceinline__ void stage_tile(const u16* __restrict__ rows, int kt, char* buf) {
    int tid = threadIdx.x;
    int w = tid >> 6, l = tid & 63;
#pragma unroll
    for (int i = 0; i < 4; ++i) {
        int sbase = i * 256 + w * 64;       // wave-uniform LDS slot base
        int sl = sbase + l;
        int row = sl >> 3;
        int c8 = (sl & 7) ^ (row & 7);      // inverse-swizzled source chunk
        const u16* src = rows + (size_t)row * 1024 + kt * 64 + c8 * 8;
        gload_lds16(src, buf + sbase * 16);
    }
}

__device__ __forceinline__ void gemm_main(
    const u16* __restrict__ Arows, const u16* __restrict__ Brows,
    char* smem, f32x4 acc[4][4])
{
    int tid = threadIdx.x;
    int l = tid & 63, lane16 = l & 15, hi = l >> 4;
    int wm = (tid >> 6) & 1, wn = tid >> 7;

    stage_tile(Arows, 0, smem);
    stage_tile(Brows, 0, smem + 16384);
    __syncthreads();
    int cur = 0;
    for (int kt = 0; kt < NKT; ++kt) {
        char* nb = smem + ((cur ^ 1) << 15);
        if (kt + 1 < NKT) { stage_tile(Arows, kt + 1, nb); stage_tile(Brows, kt + 1, nb + 16384); }
        const char* bufA = smem + (cur << 15);
        const char* bufB = bufA + 16384;
#pragma unroll
        for (int kk = 0; kk < 2; ++kk) {
            bf16x8 af[4], bb[4];
#pragma unroll
            for (int mi = 0; mi < 4; ++mi) {
                int row = wm * 64 + mi * 16 + lane16;
                int ch = (kk * 4 + hi) ^ (row & 7);
                af[mi] = *reinterpret_cast<const bf16x8*>(bufA + (row * 8 + ch) * 16);
            }
#pragma unroll
            for (int ni = 0; ni < 4; ++ni) {
                int row = wn * 64 + ni * 16 + lane16;
                int ch = (kk * 4 + hi) ^ (row & 7);
                bb[ni] = *reinterpret_cast<const bf16x8*>(bufB + (row * 8 + ch) * 16);
            }
#pragma unroll
            for (int mi = 0; mi < 4; ++mi)
#pragma unroll
                for (int ni = 0; ni < 4; ++ni)
                    acc[mi][ni] = __builtin_amdgcn_mfma_f32_16x16x32_bf16(af[mi], bb[ni], acc[mi][ni], 0, 0, 0);
        }
        __syncthreads();
        cur ^= 1;
    }
}

// ---------------- GEMM1: H = silu(Xg @ W1c + b1), bf16 out ----------------
__global__ __launch_bounds__(256, 2) void gemm1_k(
    const u16* __restrict__ Xg, const u16* __restrict__ W1c, const float* __restrict__ b1,
    int chunk, const int* __restrict__ padded_count, const int* __restrict__ poffsets,
    u16* __restrict__ H)
{
    __shared__ char smem[65536];
    int e = blockIdx.z, rb = blockIdx.y, cb = blockIdx.x;
    if (rb * TILE >= padded_count[e]) return;
    int row0 = poffsets[e] + rb * TILE;
    const u16* Arows = Xg + (size_t)row0 * 1024;
    const u16* Brows = W1c + (size_t)e * 1048576 + (size_t)cb * TILE * 1024;
    f32x4 acc[4][4];
#pragma unroll
    for (int i = 0; i < 4; ++i)
#pragma unroll
        for (int j = 0; j < 4; ++j) { acc[i][j][0]=0.f; acc[i][j][1]=0.f; acc[i][j][2]=0.f; acc[i][j][3]=0.f; }
    gemm_main(Arows, Brows, smem, acc);

    int tid = threadIdx.x;
    int l = tid & 63, lane16 = l & 15, hi = l >> 4;
    int wm = (tid >> 6) & 1, wn = tid >> 7;
    const float* b1e = b1 + (size_t)e * DFF + (size_t)chunk * CHUNK;
#pragma unroll
    for (int mi = 0; mi < 4; ++mi) {
#pragma unroll
        for (int ni = 0; ni < 4; ++ni) {
            int col = cb * TILE + wn * 64 + ni * 16 + lane16;
            float bv = b1e[col];
#pragma unroll
            for (int r = 0; r < 4; ++r) {
                int grow = row0 + wm * 64 + mi * 16 + hi * 4 + r;
                float z = acc[mi][ni][r] + bv;
                float hval = z / (1.f + __expf(-z));
                H[(size_t)grow * 1024 + col] = f2bf(hval);
            }
        }
    }
}

// ---------------- GEMM2: out[token] += w * (H @ W2c + b2), atomic scatter ----------------
__global__ __launch_bounds__(256, 2) void gemm2_k(
    const u16* __restrict__ Hb, const u16* __restrict__ W2c, const float* __restrict__ b2,
    int addbias, const int* __restrict__ expert_count, const int* __restrict__ padded_count,
    const int* __restrict__ poffsets, const int* __restrict__ list_token,
    const float* __restrict__ list_w, float* __restrict__ out)
{
    __shared__ char smem[65536];
    int e = blockIdx.z, rb = blockIdx.y, cb = blockIdx.x;
    if (rb * TILE >= padded_count[e]) return;
    int row0 = poffsets[e] + rb * TILE;
    const u16* Arows = Hb + (size_t)row0 * 1024;
    const u16* Brows = W2c + (size_t)e * 1048576 + (size_t)cb * TILE * 1024;
    f32x4 acc[4][4];
#pragma unroll
    for (int i = 0; i < 4; ++i)
#pragma unroll
        for (int j = 0; j < 4; ++j) { acc[i][j][0]=0.f; acc[i][j][1]=0.f; acc[i][j][2]=0.f; acc[i][j][3]=0.f; }
    gemm_main(Arows, Brows, smem, acc);

    int tid = threadIdx.x;
    int l = tid & 63, lane16 = l & 15, hi = l >> 4;
    int wm = (tid >> 6) & 1, wn = tid >> 7;
    int cnt = expert_count[e];
#pragma unroll
    for (int mi = 0; mi < 4; ++mi) {
#pragma unroll
        for (int r = 0; r < 4; ++r) {
            int p = rb * TILE + wm * 64 + mi * 16 + hi * 4 + r;
            if (p < cnt) {
                int tok = list_token[e * CAP + p];
                float wgt = list_w[e * CAP + p];
                float* orow = out + (size_t)tok * DM;
#pragma unroll
                for (int ni = 0; ni < 4; ++ni) {
                    int col = cb * TILE + wn * 64 + ni * 16 + lane16;
                    float v = acc[mi][ni][r];
                    if (addbias) v += b2[e * DM + col];
                    atomicAdd(orow + col, wgt * v);
                }
            }
        }
    }
}

extern "C" void kernel_launch(void* const* d_in, const int* in_sizes, int n_in,
                              void* d_out, int out_size, void* d_ws, size_t ws_size,
                              hipStream_t stream) {
    (void)in_sizes; (void)n_in; (void)out_size; (void)ws_size;
    const float* x  = (const float*)d_in[0];
    const float* Wr = (const float*)d_in[1];
    const float* br = (const float*)d_in[2];
    const float* W1 = (const float*)d_in[3];
    const float* b1 = (const float*)d_in[4];
    const float* W2 = (const float*)d_in[5];
    const float* b2 = (const float*)d_in[6];
    float* out = (float*)d_out;   // [8192*1024] out, then [1] aux

    char* ws = (char*)d_ws;
    int*   expert_count = (int*)(ws + 0);      // 32 B
    float* prob_sum     = (float*)(ws + 32);   // 32 B
    int*   padded_count = (int*)(ws + 64);     // 32 B
    int*   poffsets     = (int*)(ws + 96);     // 32 B
    int*   list_token   = (int*)(ws + 256);                // 256 KiB
    float* list_w       = (float*)(ws + 256 + 262144);     // 256 KiB
    u16*   Xg  = (u16*)(ws + 524544);       // 35,651,584
    u16*   Hb  = (u16*)(ws + 36176128);     // 35,651,584
    u16*   W1c = (u16*)(ws + 71827712);     // 16,777,216
    u16*   W2c = (u16*)(ws + 88604928);     // 16,777,216  -> total ~105.4 MB

    hipMemsetAsync(d_out, 0, (size_t)TT * DM * sizeof(float), stream);  // out accumulated atomically
    hipMemsetAsync(ws, 0, 64, stream);                                  // counts + prob sums

    router_k<<<TT / RTOK, 256, 0, stream>>>(x, Wr, br, expert_count, prob_sum, list_token, list_w);
    scan_aux_k<<<1, 64, 0, stream>>>(expert_count, prob_sum, padded_count, poffsets,
                                     out + (size_t)TT * DM);
    gather_k<<<dim3(1024, 8), 256, 0, stream>>>(x, list_token, expert_count, padded_count, poffsets, Xg);

    for (int c = 0; c < NCHUNK; ++c) {
        convt_k<<<dim3(16, 16, 8), 256, 0, stream>>>(W1, W1c, (long)c * 1024, DFF);      // W1[e][k][c*1024+j] -> [j][k]
        convt_k<<<dim3(16, 16, 8), 256, 0, stream>>>(W2, W2c, (long)c * 1048576, DM);    // W2[e][c*1024+k][j] -> [j][k]
        gemm1_k<<<dim3(8, 64, 8), 256, 0, stream>>>(Xg, W1c, b1, c, padded_count, poffsets, Hb);
        gemm2_k<<<dim3(8, 64, 8), 256, 0, stream>>>(Hb, W2c, b2, (c == 0) ? 1 : 0,
                                                    expert_count, padded_count, poffsets,
                                                    list_token, list_w, out);
    }
}

// Round 3
// 542.632 us; speedup vs baseline: 1.9093x; 1.5325x over previous
//
#include <hip/hip_runtime.h>

#define DM     1024
#define DFF    4096
#define NE     8
#define TT     8192
#define CAP    8192
#define TILE   128
#define RTOK   32
#define MAXROWS 17408   // 16384 entries + 8*127 pad, rounded up

typedef __bf16 bf16x8 __attribute__((ext_vector_type(8)));
typedef float  f32x4  __attribute__((ext_vector_type(4)));
typedef unsigned short u16;
typedef unsigned int   u32;

__device__ __forceinline__ u16 f2bf(float f) {
    u32 u = __builtin_bit_cast(u32, f);
    u += 0x7fffu + ((u >> 16) & 1u);   // round-to-nearest-even
    return (u16)(u >> 16);
}

__device__ __forceinline__ void gload_lds16(const void* g, void* l) {
    __builtin_amdgcn_global_load_lds(
        (const __attribute__((address_space(1))) void*)g,
        (__attribute__((address_space(3))) void*)l,
        16, 0, 0);
}

// ---------------- router: block-aggregated top-2 routing ----------------
__global__ __launch_bounds__(256) void router_k(
    const float* __restrict__ x, const float* __restrict__ Wr, const float* __restrict__ br,
    int* __restrict__ expert_count, float* __restrict__ prob_sum,
    int* __restrict__ list_token, float* __restrict__ list_w,
    int* __restrict__ tok_e, int* __restrict__ tok_q, float* __restrict__ tok_w)
{
    __shared__ float wrT[NE][DM];
    __shared__ float ps[NE];
    __shared__ int   lcount[NE];
    __shared__ int   lbase[NE];
    __shared__ int   lexp[RTOK * 2];
    __shared__ float lw[RTOK * 2];
    __shared__ int   lslot[RTOK * 2];

    int tid = threadIdx.x;
    if (tid < NE) { ps[tid] = 0.f; lcount[tid] = 0; }
#pragma unroll
    for (int it = 0; it < 8; ++it) {
        int f = tid * 4 + it * 1024;
        float4 v = *reinterpret_cast<const float4*>(Wr + f);
        int e0 = f & 7, k = f >> 3;
        wrT[e0][k] = v.x; wrT[e0 + 1][k] = v.y; wrT[e0 + 2][k] = v.z; wrT[e0 + 3][k] = v.w;
    }
    __syncthreads();

    int w = tid >> 6, l = tid & 63;
    for (int j = 0; j < RTOK / 4; ++j) {
        int ti = w * (RTOK / 4) + j;
        int token = blockIdx.x * RTOK + ti;
        const float* xr = x + (size_t)token * DM;
        float acc[NE];
#pragma unroll
        for (int e = 0; e < NE; ++e) acc[e] = 0.f;
#pragma unroll
        for (int i = 0; i < 4; ++i) {
            float4 xv = *reinterpret_cast<const float4*>(xr + i * 256 + l * 4);
#pragma unroll
            for (int e = 0; e < NE; ++e) {
                float4 wv = *reinterpret_cast<const float4*>(&wrT[e][i * 256 + l * 4]);
                acc[e] += xv.x * wv.x + xv.y * wv.y + xv.z * wv.z + xv.w * wv.w;
            }
        }
#pragma unroll
        for (int off = 32; off >= 1; off >>= 1) {
#pragma unroll
            for (int e = 0; e < NE; ++e) acc[e] += __shfl_xor(acc[e], off);
        }
        if (l == 0) {
            float li[NE], m = -1e30f;
#pragma unroll
            for (int e = 0; e < NE; ++e) { li[e] = (acc[e] + br[e]) * (1.0f / 0.7f); m = fmaxf(m, li[e]); }
            float p[NE], s = 0.f;
#pragma unroll
            for (int e = 0; e < NE; ++e) { p[e] = __expf(li[e] - m); s += p[e]; }
            float inv = 1.f / s;
#pragma unroll
            for (int e = 0; e < NE; ++e) { p[e] *= inv; atomicAdd(&ps[e], p[e]); }
            float v1 = -1.f, v2 = -1.f; int e1 = 0, e2 = 0;
#pragma unroll
            for (int e = 0; e < NE; ++e) {   // ascending scan: ties keep lower index (top_k semantics)
                float pe = p[e];
                if (pe > v1)      { v2 = v1; e2 = e1; v1 = pe; e1 = e; }
                else if (pe > v2) { v2 = pe; e2 = e; }
            }
            float denom = v1 + v2 + 1e-6f;
            lexp[2 * ti]     = e1; lw[2 * ti]     = v1 / denom; lslot[2 * ti]     = atomicAdd(&lcount[e1], 1);
            lexp[2 * ti + 1] = e2; lw[2 * ti + 1] = v2 / denom; lslot[2 * ti + 1] = atomicAdd(&lcount[e2], 1);
        }
    }
    __syncthreads();
    if (tid < NE) {
        lbase[tid] = atomicAdd(&expert_count[tid], lcount[tid]);
        atomicAdd(&prob_sum[tid], ps[tid]);
    }
    __syncthreads();
    if (tid < RTOK * 2) {
        int e = lexp[tid];
        int q = lbase[e] + lslot[tid];
        int token = blockIdx.x * RTOK + (tid >> 1);
        list_token[e * CAP + q] = token;
        list_w[e * CAP + q] = lw[tid];
        int slot = token * 2 + (tid & 1);
        tok_e[slot] = e; tok_q[slot] = q; tok_w[slot] = lw[tid];
    }
}

// ---------------- scan: padded offsets + aux loss ----------------
__global__ void scan_aux_k(const int* __restrict__ expert_count, const float* __restrict__ prob_sum,
                           int* __restrict__ padded_count, int* __restrict__ poffsets,
                           float* __restrict__ aux_out)
{
    if (threadIdx.x == 0 && blockIdx.x == 0) {
        int off = 0; float aux = 0.f;
        for (int e = 0; e < NE; ++e) {
            int c = expert_count[e];
            int pc = (c + TILE - 1) / TILE * TILE;
            poffsets[e] = off; padded_count[e] = pc; off += pc;
            aux += ((float)c / (float)TT) * (prob_sum[e] / (float)TT);
        }
        aux_out[0] = aux * (float)NE;
    }
}

// ---------------- gather routed x rows -> bf16 Xg ----------------
__global__ __launch_bounds__(256) void gather_k(
    const float* __restrict__ x, const int* __restrict__ list_token,
    const int* __restrict__ expert_count, const int* __restrict__ padded_count,
    const int* __restrict__ poffsets, u16* __restrict__ Xg)
{
    int e = blockIdx.y;
    int p0 = blockIdx.x * 8;
    if (p0 >= padded_count[e]) return;
    int tid = threadIdx.x;
    int rr = tid >> 5, cl = tid & 31;
    int p = p0 + rr;
    int g = poffsets[e] + p;
    u16* dst = Xg + (size_t)g * DM;
    bool valid = p < expert_count[e];
    int tok = valid ? list_token[e * CAP + p] : 0;
    const float* src = x + (size_t)tok * DM;
#pragma unroll
    for (int i = 0; i < 4; ++i) {
        int c0 = cl * 8 + i * 256;
        uint4 v;
        if (valid) {
            float4 f0 = *reinterpret_cast<const float4*>(src + c0);
            float4 f1 = *reinterpret_cast<const float4*>(src + c0 + 4);
            v.x = f2bf(f0.x) | ((u32)f2bf(f0.y) << 16);
            v.y = f2bf(f0.z) | ((u32)f2bf(f0.w) << 16);
            v.z = f2bf(f1.x) | ((u32)f2bf(f1.y) << 16);
            v.w = f2bf(f1.z) | ((u32)f2bf(f1.w) << 16);
        } else {
            v.x = 0; v.y = 0; v.z = 0; v.w = 0;
        }
        *reinterpret_cast<uint4*>(dst + c0) = v;
    }
}

// ---------------- transpose + fp32->bf16 convert: src[e][base + k*rs + j] -> dst[e][j*Ktot + k] ----------------
__global__ __launch_bounds__(256) void convt_k(
    const float* __restrict__ src, u16* __restrict__ dst, long base, int rs, int Ktot, long dstEStride)
{
    __shared__ float tile[64][65];
    int e = blockIdx.z;
    int k0 = blockIdx.x * 64, j0 = blockIdx.y * 64;
    const float* s = src + (size_t)e * 4194304 + base;
    int tid = threadIdx.x;
    {
        int jj = (tid & 15) * 4, kb = tid >> 4;
#pragma unroll
        for (int i = 0; i < 4; ++i) {
            int k = kb + i * 16;
            float4 v = *reinterpret_cast<const float4*>(s + (size_t)(k0 + k) * rs + j0 + jj);
            tile[k][jj] = v.x; tile[k][jj + 1] = v.y; tile[k][jj + 2] = v.z; tile[k][jj + 3] = v.w;
        }
    }
    __syncthreads();
    {
        int kk = (tid & 15) * 4, jb = tid >> 4;
        u16* d = dst + (size_t)e * dstEStride;
#pragma unroll
        for (int i = 0; i < 4; ++i) {
            int j = jb + i * 16;
            uint2 q;
            q.x = f2bf(tile[kk][j])     | ((u32)f2bf(tile[kk + 1][j]) << 16);
            q.y = f2bf(tile[kk + 2][j]) | ((u32)f2bf(tile[kk + 3][j]) << 16);
            *reinterpret_cast<uint2*>(d + (size_t)(j0 + j) * Ktot + k0 + kk) = q;
        }
    }
}

// ---------------- 128x128 bf16 GEMM mainloop (single-buffer, gload_lds, runtime K) ----------------
__device__ __forceinline__ void stage_tile(const u16* __restrict__ rows, long lda, int kt, char* buf) {
    int tid = threadIdx.x;
    int w = tid >> 6, l = tid & 63;
#pragma unroll
    for (int i = 0; i < 4; ++i) {
        int sbase = i * 256 + w * 64;       // wave-uniform LDS slot base
        int sl = sbase + l;
        int row = sl >> 3;
        int c8 = (sl & 7) ^ (row & 7);      // inverse-swizzled source chunk (pairs with read-side XOR)
        const u16* src = rows + (size_t)row * lda + kt * 64 + c8 * 8;
        gload_lds16(src, buf + sbase * 16);
    }
}

__device__ __forceinline__ void gemm_main(
    const u16* __restrict__ Arows, long lda,
    const u16* __restrict__ Brows, long ldb,
    int nkt, char* smem, f32x4 acc[4][4])
{
    int tid = threadIdx.x;
    int l = tid & 63, lane16 = l & 15, hi = l >> 4;
    int wm = (tid >> 6) & 1, wn = tid >> 7;

    for (int kt = 0; kt < nkt; ++kt) {
        stage_tile(Arows, lda, kt, smem);
        stage_tile(Brows, ldb, kt, smem + 16384);
        __syncthreads();
        const char* bufA = smem;
        const char* bufB = smem + 16384;
#pragma unroll
        for (int kk = 0; kk < 2; ++kk) {
            bf16x8 af[4], bb[4];
#pragma unroll
            for (int mi = 0; mi < 4; ++mi) {
                int row = wm * 64 + mi * 16 + lane16;
                int ch = (kk * 4 + hi) ^ (row & 7);
                af[mi] = *reinterpret_cast<const bf16x8*>(bufA + (row * 8 + ch) * 16);
            }
#pragma unroll
            for (int ni = 0; ni < 4; ++ni) {
                int row = wn * 64 + ni * 16 + lane16;
                int ch = (kk * 4 + hi) ^ (row & 7);
                bb[ni] = *reinterpret_cast<const bf16x8*>(bufB + (row * 8 + ch) * 16);
            }
#pragma unroll
            for (int mi = 0; mi < 4; ++mi)
#pragma unroll
                for (int ni = 0; ni < 4; ++ni)
                    acc[mi][ni] = __builtin_amdgcn_mfma_f32_16x16x32_bf16(af[mi], bb[ni], acc[mi][ni], 0, 0, 0);
        }
        __syncthreads();
    }
}

// ---------------- GEMM1: H = silu(Xg @ W1c + b1), bf16, N range = CHUNK ----------------
__global__ __launch_bounds__(256, 4) void gemm1_k(
    const u16* __restrict__ Xg, const u16* __restrict__ W1c, const float* __restrict__ b1,
    int ffBase, int chunkN, const int* __restrict__ padded_count, const int* __restrict__ poffsets,
    u16* __restrict__ H)
{
    __shared__ char smem[32768];
    int e = blockIdx.z, rb = blockIdx.y, cb = blockIdx.x;
    if (rb * TILE >= padded_count[e]) return;
    int row0 = poffsets[e] + rb * TILE;
    const u16* Arows = Xg + (size_t)row0 * 1024;
    const u16* Brows = W1c + (size_t)e * chunkN * 1024 + (size_t)cb * TILE * 1024;
    f32x4 acc[4][4];
#pragma unroll
    for (int i = 0; i < 4; ++i)
#pragma unroll
        for (int j = 0; j < 4; ++j) { acc[i][j][0]=0.f; acc[i][j][1]=0.f; acc[i][j][2]=0.f; acc[i][j][3]=0.f; }
    gemm_main(Arows, 1024, Brows, 1024, 16, smem, acc);

    int tid = threadIdx.x;
    int l = tid & 63, lane16 = l & 15, hi = l >> 4;
    int wm = (tid >> 6) & 1, wn = tid >> 7;
    const float* b1e = b1 + (size_t)e * DFF + ffBase;
#pragma unroll
    for (int mi = 0; mi < 4; ++mi) {
#pragma unroll
        for (int ni = 0; ni < 4; ++ni) {
            int col = cb * TILE + wn * 64 + ni * 16 + lane16;
            float bv = b1e[col];
#pragma unroll
            for (int r = 0; r < 4; ++r) {
                int grow = row0 + wm * 64 + mi * 16 + hi * 4 + r;
                float z = acc[mi][ni][r] + bv;
                float hval = z / (1.f + __expf(-z));
                H[(size_t)grow * chunkN + col] = f2bf(hval);
            }
        }
    }
}

// ---------------- GEMM2: Og[row] (+)= Hchunk @ W2c ; or legacy atomic scatter ----------------
// mode 0: Og store; mode 1: Og accumulate; mode 2: atomic scatter + bias; mode 3: atomic scatter no bias
__global__ __launch_bounds__(256, 4) void gemm2_k(
    const u16* __restrict__ Hb, const u16* __restrict__ W2c, const float* __restrict__ b2,
    int chunkK, int mode, const int* __restrict__ expert_count, const int* __restrict__ padded_count,
    const int* __restrict__ poffsets, const int* __restrict__ list_token,
    const float* __restrict__ list_w, float* __restrict__ Og, float* __restrict__ out)
{
    __shared__ char smem[32768];
    int e = blockIdx.z, rb = blockIdx.y, cb = blockIdx.x;
    if (rb * TILE >= padded_count[e]) return;
    int row0 = poffsets[e] + rb * TILE;
    const u16* Arows = Hb + (size_t)row0 * chunkK;
    const u16* Brows = W2c + (size_t)e * DM * chunkK + (size_t)cb * TILE * chunkK;
    f32x4 acc[4][4];
#pragma unroll
    for (int i = 0; i < 4; ++i)
#pragma unroll
        for (int j = 0; j < 4; ++j) { acc[i][j][0]=0.f; acc[i][j][1]=0.f; acc[i][j][2]=0.f; acc[i][j][3]=0.f; }
    gemm_main(Arows, chunkK, Brows, chunkK, chunkK >> 6, smem, acc);

    int tid = threadIdx.x;
    int l = tid & 63, lane16 = l & 15, hi = l >> 4;
    int wm = (tid >> 6) & 1, wn = tid >> 7;
    if (mode <= 1) {
#pragma unroll
        for (int mi = 0; mi < 4; ++mi) {
#pragma unroll
            for (int r = 0; r < 4; ++r) {
                int grow = row0 + wm * 64 + mi * 16 + hi * 4 + r;
                float* orow = Og + (size_t)grow * DM;
#pragma unroll
                for (int ni = 0; ni < 4; ++ni) {
                    int col = cb * TILE + wn * 64 + ni * 16 + lane16;
                    float v = acc[mi][ni][r];
                    if (mode == 1) v += orow[col];
                    orow[col] = v;
                }
            }
        }
    } else {
        int cnt = expert_count[e];
#pragma unroll
        for (int mi = 0; mi < 4; ++mi) {
#pragma unroll
            for (int r = 0; r < 4; ++r) {
                int p = rb * TILE + wm * 64 + mi * 16 + hi * 4 + r;
                if (p < cnt) {
                    int tok = list_token[e * CAP + p];
                    float wgt = list_w[e * CAP + p];
                    float* orow = out + (size_t)tok * DM;
#pragma unroll
                    for (int ni = 0; ni < 4; ++ni) {
                        int col = cb * TILE + wn * 64 + ni * 16 + lane16;
                        float v = acc[mi][ni][r];
                        if (mode == 2) v += b2[e * DM + col];
                        atomicAdd(orow + col, wgt * v);
                    }
                }
            }
        }
    }
}

// ---------------- combine: out[t] = sum_r w_r * (Og[row_r] + b2[e_r]) ----------------
__global__ __launch_bounds__(256) void combine_k(
    const float* __restrict__ Og, const float* __restrict__ b2,
    const int* __restrict__ tok_e, const int* __restrict__ tok_q, const float* __restrict__ tok_w,
    const int* __restrict__ poffsets, float* __restrict__ out)
{
    int t = blockIdx.x * 4 + (threadIdx.x >> 6);
    int l = threadIdx.x & 63;
    int e0 = tok_e[t * 2], q0 = tok_q[t * 2];
    int e1 = tok_e[t * 2 + 1], q1 = tok_q[t * 2 + 1];
    float w0 = tok_w[t * 2], w1 = tok_w[t * 2 + 1];
    const float* r0 = Og + (size_t)(poffsets[e0] + q0) * DM;
    const float* r1 = Og + (size_t)(poffsets[e1] + q1) * DM;
    const float* bb0 = b2 + (size_t)e0 * DM;
    const float* bb1 = b2 + (size_t)e1 * DM;
    float* o = out + (size_t)t * DM;
#pragma unroll
    for (int i = 0; i < 4; ++i) {
        int c = l * 4 + i * 256;
        float4 a = *reinterpret_cast<const float4*>(r0 + c);
        float4 b = *reinterpret_cast<const float4*>(r1 + c);
        float4 p = *reinterpret_cast<const float4*>(bb0 + c);
        float4 q = *reinterpret_cast<const float4*>(bb1 + c);
        float4 res;
        res.x = w0 * (a.x + p.x) + w1 * (b.x + q.x);
        res.y = w0 * (a.y + p.y) + w1 * (b.y + q.y);
        res.z = w0 * (a.z + p.z) + w1 * (b.z + q.z);
        res.w = w0 * (a.w + p.w) + w1 * (b.w + q.w);
        *reinterpret_cast<float4*>(o + c) = res;
    }
}

extern "C" void kernel_launch(void* const* d_in, const int* in_sizes, int n_in,
                              void* d_out, int out_size, void* d_ws, size_t ws_size,
                              hipStream_t stream) {
    (void)in_sizes; (void)n_in; (void)out_size;
    const float* x  = (const float*)d_in[0];
    const float* Wr = (const float*)d_in[1];
    const float* br = (const float*)d_in[2];
    const float* W1 = (const float*)d_in[3];
    const float* b1 = (const float*)d_in[4];
    const float* W2 = (const float*)d_in[5];
    const float* b2 = (const float*)d_in[6];
    float* out = (float*)d_out;   // [8192*1024] out, then [1] aux

    char* ws = (char*)d_ws;
    int*   expert_count = (int*)(ws + 0);
    float* prob_sum     = (float*)(ws + 32);
    int*   padded_count = (int*)(ws + 64);
    int*   poffsets     = (int*)(ws + 96);
    int*   list_token   = (int*)(ws + 256);                 // 256 KiB
    float* list_w       = (float*)(ws + 256 + 262144);      // 256 KiB
    int*   tok_e        = (int*)(ws + 524544);              // 64 KiB
    int*   tok_q        = (int*)(ws + 524544 + 65536);      // 64 KiB
    float* tok_w        = (float*)(ws + 524544 + 131072);   // 64 KiB
    const size_t HDR = 1048576;
    u16* Xg = (u16*)(ws + HDR);                             // 35,651,584

    // layout variants
    const size_t XG_B   = (size_t)MAXROWS * DM * 2;
    const size_t OG_B   = (size_t)MAXROWS * DM * 4;

    // Full path: CHUNK=4096. Hb[rows][4096], W2c full, W1c full, Og aliased over W1c.
    const size_t F_HB   = HDR + XG_B;                       // 142,606,336
    const size_t F_W2   = F_HB + (size_t)MAXROWS * DFF * 2; // 67,108,864
    const size_t F_W1   = F_W2 + (size_t)NE * DM * DFF * 2; // 67,108,864
    const size_t F_OG   = F_W1;                             // alias (W1c dead before gemm2)
    const size_t F_NEED = F_OG + OG_B;                      // ~317.7 MB

    // Mid path: CHUNK=1024 with Og combine.
    const size_t M_HB   = HDR + XG_B;
    const size_t M_W2   = M_HB + (size_t)MAXROWS * 1024 * 2;
    const size_t M_W1   = M_W2 + (size_t)NE * DM * 1024 * 2;
    const size_t M_OG   = M_W1 + (size_t)NE * DM * 1024 * 2;
    const size_t M_NEED = M_OG + OG_B;                      // ~177.2 MB

    hipMemsetAsync(ws, 0, 64, stream);
    router_k<<<TT / RTOK, 256, 0, stream>>>(x, Wr, br, expert_count, prob_sum, list_token, list_w,
                                            tok_e, tok_q, tok_w);
    scan_aux_k<<<1, 64, 0, stream>>>(expert_count, prob_sum, padded_count, poffsets,
                                     out + (size_t)TT * DM);
    gather_k<<<dim3(1024, 8), 256, 0, stream>>>(x, list_token, expert_count, padded_count, poffsets, Xg);

    if (ws_size >= F_NEED) {
        u16* Hb  = (u16*)(ws + F_HB);
        u16* W2c = (u16*)(ws + F_W2);
        u16* W1c = (u16*)(ws + F_W1);
        float* Og = (float*)(ws + F_OG);
        // W1[e][k<1024][j<4096] -> W1c[e][j][k], Ktot=1024
        convt_k<<<dim3(16, 64, 8), 256, 0, stream>>>(W1, W1c, 0, DFF, 1024, (long)DM * DFF);
        // W2[e][k<4096][j<1024] -> W2c[e][j][k], Ktot=4096
        convt_k<<<dim3(64, 16, 8), 256, 0, stream>>>(W2, W2c, 0, DM, 4096, (long)DM * DFF);
        gemm1_k<<<dim3(32, 64, 8), 256, 0, stream>>>(Xg, W1c, b1, 0, DFF, padded_count, poffsets, Hb);
        gemm2_k<<<dim3(8, 64, 8), 256, 0, stream>>>(Hb, W2c, b2, DFF, 0, expert_count, padded_count,
                                                    poffsets, list_token, list_w, Og, out);
        combine_k<<<TT / 4, 256, 0, stream>>>(Og, b2, tok_e, tok_q, tok_w, poffsets, out);
    } else if (ws_size >= M_NEED) {
        u16* Hb  = (u16*)(ws + M_HB);
        u16* W2c = (u16*)(ws + M_W2);
        u16* W1c = (u16*)(ws + M_W1);
        float* Og = (float*)(ws + M_OG);
        for (int c = 0; c < 4; ++c) {
            convt_k<<<dim3(16, 16, 8), 256, 0, stream>>>(W1, W1c, (long)c * 1024, DFF, 1024, (long)DM * 1024);
            convt_k<<<dim3(16, 16, 8), 256, 0, stream>>>(W2, W2c, (long)c * 1024 * 1024, DM, 1024, (long)DM * 1024);
            gemm1_k<<<dim3(8, 64, 8), 256, 0, stream>>>(Xg, W1c, b1, c * 1024, 1024, padded_count, poffsets, Hb);
            gemm2_k<<<dim3(8, 64, 8), 256, 0, stream>>>(Hb, W2c, b2, 1024, (c == 0) ? 0 : 1,
                                                        expert_count, padded_count, poffsets,
                                                        list_token, list_w, Og, out);
        }
        combine_k<<<TT / 4, 256, 0, stream>>>(Og, b2, tok_e, tok_q, tok_w, poffsets, out);
    } else {
        // legacy atomic path (~105 MB)
        u16* Hb  = (u16*)(ws + M_HB);
        u16* W2c = (u16*)(ws + M_W2);
        u16* W1c = (u16*)(ws + M_W1);
        hipMemsetAsync(d_out, 0, (size_t)TT * DM * sizeof(float), stream);
        for (int c = 0; c < 4; ++c) {
            convt_k<<<dim3(16, 16, 8), 256, 0, stream>>>(W1, W1c, (long)c * 1024, DFF, 1024, (long)DM * 1024);
            convt_k<<<dim3(16, 16, 8), 256, 0, stream>>>(W2, W2c, (long)c * 1024 * 1024, DM, 1024, (long)DM * 1024);
            gemm1_k<<<dim3(8, 64, 8), 256, 0, stream>>>(Xg, W1c, b1, c * 1024, 1024, padded_count, poffsets, Hb);
            gemm2_k<<<dim3(8, 64, 8), 256, 0, stream>>>(Hb, W2c, b2, 1024, (c == 0) ? 2 : 3,
                                                        expert_count, padded_count, poffsets,
                                                        list_token, list_w, nullptr, out);
        }
    }
}